// Round 3
// baseline (235.814 us; speedup 1.0000x reference)
//
#include <hip/hip_runtime.h>

// Covariance from (scales, quaternion) — 3D Gaussian splatting head.
// out[n] = upper-tri(R diag(s^2) R^T) with R from normalized quat.
// Memory-bound. 4 rows/thread: scales = 3x float4, rots = 4x float4,
// out = 6x float4 (nontemporal — write-once stream, keep L2/L3 for inputs).

typedef float f32x4 __attribute__((ext_vector_type(4)));  // native vec for nontemporal builtin

__device__ __forceinline__ void cov6(float r, float x, float y, float z,
                                     float s0, float s1, float s2,
                                     float* __restrict__ o) {
    float inv = rsqrtf(r * r + x * x + y * y + z * z);
    r *= inv; x *= inv; y *= inv; z *= inv;
    float R00 = 1.f - 2.f * (y * y + z * z);
    float R01 = 2.f * (x * y - r * z);
    float R02 = 2.f * (x * z + r * y);
    float R10 = 2.f * (x * y + r * z);
    float R11 = 1.f - 2.f * (x * x + z * z);
    float R12 = 2.f * (y * z - r * x);
    float R20 = 2.f * (x * z - r * y);
    float R21 = 2.f * (y * z + r * x);
    float R22 = 1.f - 2.f * (x * x + y * y);
    float a = s0 * s0, b = s1 * s1, c = s2 * s2;
    o[0] = R00 * R00 * a + R01 * R01 * b + R02 * R02 * c;  // cov00
    o[1] = R00 * R10 * a + R01 * R11 * b + R02 * R12 * c;  // cov01
    o[2] = R00 * R20 * a + R01 * R21 * b + R02 * R22 * c;  // cov02
    o[3] = R10 * R10 * a + R11 * R11 * b + R12 * R12 * c;  // cov11
    o[4] = R10 * R20 * a + R11 * R21 * b + R12 * R22 * c;  // cov12
    o[5] = R20 * R20 * a + R21 * R21 * b + R22 * R22 * c;  // cov22
}

__global__ __launch_bounds__(256) void gaus_cov_kernel4(
    const float* __restrict__ scales,  // (N,3)
    const float* __restrict__ rots,    // (N,4)
    float* __restrict__ out,           // (N,6)
    int n, int nquads) {
    int t = blockIdx.x * blockDim.x + threadIdx.x;
    if (t >= nquads) return;
    long long row = 4ll * t;
    if (row + 3 < n) {
        // Fast path: 4 rows, all accesses float4 & 16B-aligned.
        const float4* sp = reinterpret_cast<const float4*>(scales + 12ll * t);
        float4 s0 = sp[0], s1 = sp[1], s2 = sp[2];
        const float4* rp = reinterpret_cast<const float4*>(rots + 16ll * t);
        float4 q0 = rp[0], q1 = rp[1], q2 = rp[2], q3 = rp[3];
        float o[24];
        cov6(q0.x, q0.y, q0.z, q0.w, s0.x, s0.y, s0.z, o);
        cov6(q1.x, q1.y, q1.z, q1.w, s0.w, s1.x, s1.y, o + 6);
        cov6(q2.x, q2.y, q2.z, q2.w, s1.z, s1.w, s2.x, o + 12);
        cov6(q3.x, q3.y, q3.z, q3.w, s2.y, s2.z, s2.w, o + 18);
        f32x4* op = reinterpret_cast<f32x4*>(out + 24ll * t);
        #pragma unroll
        for (int i = 0; i < 6; ++i) {
            f32x4 v = {o[4 * i], o[4 * i + 1], o[4 * i + 2], o[4 * i + 3]};
            __builtin_nontemporal_store(v, op + i);
        }
    } else {
        // Tail (n % 4 != 0): scalar per-row path.
        for (; row < n; ++row) {
            float a0 = scales[3ll * row + 0];
            float a1 = scales[3ll * row + 1];
            float a2 = scales[3ll * row + 2];
            const float4* rp = reinterpret_cast<const float4*>(rots + 4ll * row);
            float4 q = rp[0];
            float o[6];
            cov6(q.x, q.y, q.z, q.w, a0, a1, a2, o);
            float* op = out + 6ll * row;
            op[0] = o[0]; op[1] = o[1]; op[2] = o[2];
            op[3] = o[3]; op[4] = o[4]; op[5] = o[5];
        }
    }
}

extern "C" void kernel_launch(void* const* d_in, const int* in_sizes, int n_in,
                              void* d_out, int out_size, void* d_ws, size_t ws_size,
                              hipStream_t stream) {
    const float* scales = (const float*)d_in[0];
    const float* rots   = (const float*)d_in[1];
    float* out = (float*)d_out;
    int n = in_sizes[0] / 3;           // N rows
    int nquads = (n + 3) / 4;
    int block = 256;
    int grid = (nquads + block - 1) / block;
    gaus_cov_kernel4<<<grid, block, 0, stream>>>(scales, rots, out, n, nquads);
}

// Round 4
// 42.826 us; speedup vs baseline: 5.5064x; 5.5064x over previous
//
#include <hip/hip_runtime.h>

// Covariance from (scales, quaternion) — 3D Gaussian splatting head.
// out[n] = upper-tri(R diag(s^2) R^T) with R from normalized quat.
// Memory-bound. 4 rows/thread. Output staged through LDS so nontemporal
// global stores are lane-contiguous (4KB/wave-instruction): no partial-line
// write amplification (R3 lesson: strided nt stores -> 2.9x WRITE_SIZE) and
// no L2/L3 pollution, keeping the 143MB of inputs L3-resident across replays.

typedef float f32x4 __attribute__((ext_vector_type(4)));

__device__ __forceinline__ void cov6(float r, float x, float y, float z,
                                     float s0, float s1, float s2,
                                     float* __restrict__ o) {
    float inv = rsqrtf(r * r + x * x + y * y + z * z);
    r *= inv; x *= inv; y *= inv; z *= inv;
    float R00 = 1.f - 2.f * (y * y + z * z);
    float R01 = 2.f * (x * y - r * z);
    float R02 = 2.f * (x * z + r * y);
    float R10 = 2.f * (x * y + r * z);
    float R11 = 1.f - 2.f * (x * x + z * z);
    float R12 = 2.f * (y * z - r * x);
    float R20 = 2.f * (x * z - r * y);
    float R21 = 2.f * (y * z + r * x);
    float R22 = 1.f - 2.f * (x * x + y * y);
    float a = s0 * s0, b = s1 * s1, c = s2 * s2;
    o[0] = R00 * R00 * a + R01 * R01 * b + R02 * R02 * c;  // cov00
    o[1] = R00 * R10 * a + R01 * R11 * b + R02 * R12 * c;  // cov01
    o[2] = R00 * R20 * a + R01 * R21 * b + R02 * R22 * c;  // cov02
    o[3] = R10 * R10 * a + R11 * R11 * b + R12 * R12 * c;  // cov11
    o[4] = R10 * R20 * a + R11 * R21 * b + R12 * R22 * c;  // cov12
    o[5] = R20 * R20 * a + R21 * R21 * b + R22 * R22 * c;  // cov22
}

// XOR swizzle: flips bit0 of the float4 index iff bit3 is set. Involution.
// Write side (stride-6 float4 per lane) hits all 8 superbanks uniformly;
// read side (stride-1) stays uniform.
__device__ __forceinline__ int swz(int g) { return g ^ ((g >> 3) & 1); }

__global__ __launch_bounds__(256) void gaus_cov_lds(
    const float* __restrict__ scales,  // (N,3)
    const float* __restrict__ rots,    // (N,4)
    float* __restrict__ out,           // (N,6)
    int n) {
    __shared__ f32x4 lds[1536];        // 1024 rows * 6 f32 = 24 KB
    const int t = threadIdx.x;
    const long long blockRow = 1024ll * blockIdx.x;

    if (blockRow + 1024 <= n) {
        // Fast path: whole block in range. 4 rows/thread, all I/O float4.
        const long long gt = blockRow / 4 + t;           // global quad index
        const float4* sp = reinterpret_cast<const float4*>(scales + 12ll * gt);
        float4 s0 = sp[0], s1 = sp[1], s2 = sp[2];
        const float4* rp = reinterpret_cast<const float4*>(rots + 16ll * gt);
        float4 q0 = rp[0], q1 = rp[1], q2 = rp[2], q3 = rp[3];
        float o[24];
        cov6(q0.x, q0.y, q0.z, q0.w, s0.x, s0.y, s0.z, o);
        cov6(q1.x, q1.y, q1.z, q1.w, s0.w, s1.x, s1.y, o + 6);
        cov6(q2.x, q2.y, q2.z, q2.w, s1.z, s1.w, s2.x, o + 12);
        cov6(q3.x, q3.y, q3.z, q3.w, s2.y, s2.z, s2.w, o + 18);
        #pragma unroll
        for (int j = 0; j < 6; ++j) {
            f32x4 v = {o[4 * j], o[4 * j + 1], o[4 * j + 2], o[4 * j + 3]};
            lds[swz(6 * t + j)] = v;
        }
        __syncthreads();
        // Coalesced nontemporal stores: lanes contiguous, 4KB per wave-instr.
        f32x4* op = reinterpret_cast<f32x4*>(out) + 1536ll * blockIdx.x;
        #pragma unroll
        for (int k = 0; k < 6; ++k) {
            int g = t + 256 * k;
            f32x4 v = lds[swz(g)];
            __builtin_nontemporal_store(v, op + g);
        }
    } else {
        // Tail block (n % 1024 != 0): scalar per-row, plain stores.
        for (int rr = 0; rr < 4; ++rr) {
            long long r = blockRow + 4ll * t + rr;
            if (r >= n) break;
            float a0 = scales[3ll * r + 0];
            float a1 = scales[3ll * r + 1];
            float a2 = scales[3ll * r + 2];
            const float4* rp = reinterpret_cast<const float4*>(rots + 4ll * r);
            float4 q = rp[0];
            float o[6];
            cov6(q.x, q.y, q.z, q.w, a0, a1, a2, o);
            float* op = out + 6ll * r;
            op[0] = o[0]; op[1] = o[1]; op[2] = o[2];
            op[3] = o[3]; op[4] = o[4]; op[5] = o[5];
        }
    }
}

extern "C" void kernel_launch(void* const* d_in, const int* in_sizes, int n_in,
                              void* d_out, int out_size, void* d_ws, size_t ws_size,
                              hipStream_t stream) {
    const float* scales = (const float*)d_in[0];
    const float* rots   = (const float*)d_in[1];
    float* out = (float*)d_out;
    int n = in_sizes[0] / 3;           // N rows
    int nblocks = (int)((n + 1023ll) / 1024ll);
    gaus_cov_lds<<<nblocks, 256, 0, stream>>>(scales, rots, out, n);
}